// Round 9
// baseline (129.920 us; speedup 1.0000x reference)
//
#include <hip/hip_runtime.h>
#include <hip/hip_bf16.h>
#include <cstdint>
#include <cstddef>

typedef unsigned short u16;
typedef __attribute__((ext_vector_type(8))) short bf16x8;
typedef __attribute__((ext_vector_type(4))) float f32x4;

constexpr int Bn = 4;
constexpr int Nq = 8192;
constexpr int Mk = 2048;
constexpr int C1c = 128;
constexpr int C2c = 256;
constexpr int H1c = 256;
constexpr int H2c = 128;

__device__ __forceinline__ float bf2f(u16 u) {
    union { uint32_t i; float f; } v;
    v.i = (uint32_t)u << 16;
    return v.f;
}
__device__ __forceinline__ u16 f2bf(float f) {
    const uint32_t x = __float_as_uint(f);
    return (u16)((x + 0x7FFFu + ((x >> 16) & 1u)) >> 16);
}
__device__ __forceinline__ uint32_t cvtpk(float lo, float hi) {
    uint32_t r;
    asm("v_cvt_pk_bf16_f32 %0, %1, %2" : "=v"(r) : "v"(lo), "v"(hi));
    return r;
}

// ================= K1: knn + f32 gemm1 + prep (cvt W1/W2, transpose UF) =================
// block ranges (knn FIRST — long pole starts at t=0):
// [0,2048) knn | [2048,2304) gemm1 f32 (KF,W1 -> Ptb bf16) | [2304,2432) cvt W | [2432,3456) UF
__global__ __launch_bounds__(256) void knn_prep_kernel(
    const float* __restrict__ W1, const float* __restrict__ W2,
    u16* __restrict__ W1b, u16* __restrict__ W2b,
    const float* __restrict__ KF, u16* __restrict__ Ptb,
    const float* __restrict__ UF, u16* __restrict__ UFt,
    const float* __restrict__ unknown, const float* __restrict__ known,
    int* __restrict__ idx_out, float* __restrict__ w_out)
{
    __shared__ __align__(16) char smem[32768];
    const int bid = blockIdx.x;
    const int t = threadIdx.x;

    if (bid < 2048) {
        // ---- 3-NN: exact f32 compare, 16 lanes/query, paired candidates ----
        float4* kp = (float4*)smem;  // (x, y, z, |k|^2), 32 KB
        const int b = bid >> 9;
        const int n0 = (bid & 511) * 16;

        const float* kb = known + (size_t)b * Mk * 3;
        for (int i = t; i < Mk; i += 256) {
            const float x = kb[i * 3 + 0], y = kb[i * 3 + 1], z = kb[i * 3 + 2];
            kp[i] = make_float4(x, y, z, fmaf(x, x, fmaf(y, y, z * z)));
        }
        __syncthreads();

        const int q = n0 + (t >> 4);
        const int s = t & 15;
        const float* u = unknown + ((size_t)b * Nq + q) * 3;
        const float ux = u[0], uy = u[1], uz = u[2];
        const float nux = -2.0f * ux, nuy = -2.0f * uy, nuz = -2.0f * uz;
        const float uu = fmaf(ux, ux, fmaf(uy, uy, uz * uz));

        // track d' = |k|^2 - 2 u.k  (ordering identical to true squared distance)
        float d0 = 1e30f, d1 = 1e30f, d2 = 1e30f;
        int i0 = 0, i1 = 0, i2 = 0;

        // full sorted-3 insert
        auto ins = [&](float d, int i) {
            const bool c0 = d < d0, c1 = d < d1, c2 = d < d2;
            const float nd0 = fminf(d0, d);
            const float nd1 = __builtin_amdgcn_fmed3f(d0, d, d1);
            const float nd2 = __builtin_amdgcn_fmed3f(d1, d, d2);
            i2 = c1 ? i1 : (c2 ? i : i2);
            i1 = c0 ? i0 : (c1 ? i : i1);
            i0 = c0 ? i : i0;
            d0 = nd0; d1 = nd1; d2 = nd2;
        };
        // insert known >= current d0 (skips slot 0)
        auto ins_hi = [&](float d, int i) {
            const bool c1 = d < d1, c2 = d < d2;
            const float nd1 = fminf(d1, d);
            const float nd2 = __builtin_amdgcn_fmed3f(d1, d, d2);
            i2 = c1 ? i1 : (c2 ? i : i2);
            i1 = c1 ? i : i1;
            d1 = nd1; d2 = nd2;
        };
        // insert known >= current d1 (slot 2 only)
        auto ins_top = [&](float d, int i) {
            const bool c2 = d < d2;
            d2 = fminf(d2, d);
            i2 = c2 ? i : i2;
        };

        #pragma unroll 4
        for (int it = 0; it < Mk / 32; ++it) {
            const int ma = it * 16 + s;       // first half  [0,1024)
            const int mb = ma + 1024;         // second half (offset:16384 in LDS)
            const float4 pa = kp[ma];
            const float4 pb = kp[mb];
            const float da = fmaf(nux, pa.x, fmaf(nuy, pa.y, fmaf(nuz, pa.z, pa.w)));
            const float db = fmaf(nux, pb.x, fmaf(nuy, pb.y, fmaf(nuz, pb.z, pb.w)));
            const bool cab = da < db;
            const float dlo = fminf(da, db), dhi = fmaxf(da, db);
            const int ilo = cab ? ma : mb, ihi = cab ? mb : ma;
            ins(dlo, ilo);
            ins_hi(dhi, ihi);   // dhi >= dlo >= new d0: can't take slot 0
        }
        // butterfly merge over 16 slice-lanes (partner triple is sorted)
        #pragma unroll
        for (int off = 1; off <= 8; off <<= 1) {
            const float e0 = __shfl_xor(d0, off), e1 = __shfl_xor(d1, off), e2 = __shfl_xor(d2, off);
            const int j0 = __shfl_xor(i0, off), j1 = __shfl_xor(i1, off), j2 = __shfl_xor(i2, off);
            ins(e0, j0);
            ins_hi(e1, j1);   // e1 >= e0 >= new d0
            ins_top(e2, j2);  // e2 >= e1 >= new d1
        }
        if (s == 0) {
            const float f0 = d0 + uu, f1 = d1 + uu, f2 = d2 + uu;
            const float r0 = 1.0f / (f0 + 1e-8f);
            const float r1 = 1.0f / (f1 + 1e-8f);
            const float r2 = 1.0f / (f2 + 1e-8f);
            const float inv = 1.0f / (r0 + r1 + r2);
            const size_t base = ((size_t)b * Nq + q) * 3;
            idx_out[base + 0] = i0;
            idx_out[base + 1] = i1;
            idx_out[base + 2] = i2;
            w_out[base + 0] = r0 * inv;
            w_out[base + 1] = r1 * inv;
            w_out[base + 2] = r2 * inv;
        }
    } else if (bid < 2304) {
        // ---- f32 gemm1: Ptb[b][m][h] = sum_c KF[b][c][m] * W1[h][c], bf16 out ----
        float (*Xs)[128] = (float(*)[128])smem;           // 16k x 128m, 8KB
        float (*Ws)[65] = (float(*)[65])(smem + 8192);    // 16k x 64h (+pad), 4.2KB
        const int f = bid - 2048;
        const int b = f >> 6;
        const int rem = f & 63;
        const int m0 = (rem >> 2) * 128;
        const int h0 = (rem & 3) * 64;
        const float* Xb = KF + (size_t)b * C2c * Mk;
        const int tx = t & 15, ty = t >> 4;

        float acc[8][4] = {};
        for (int k0 = 0; k0 < C2c; k0 += 16) {
            {
                const int mx = (t & 31) * 4, kx = t >> 5;
                #pragma unroll
                for (int i = 0; i < 2; ++i)
                    *(float4*)&Xs[kx + i * 8][mx] =
                        *(const float4*)&Xb[(size_t)(k0 + kx + i * 8) * Mk + m0 + mx];
            }
            {
                const int kw = t & 15, hw = t >> 4;
                #pragma unroll
                for (int i = 0; i < 4; ++i)
                    Ws[kw][hw + i * 16] = W1[(size_t)(h0 + hw + i * 16) * 384 + k0 + kw];
            }
            __syncthreads();
            #pragma unroll
            for (int k = 0; k < 16; ++k) {
                float a[8], bv[4];
                *(float4*)&a[0] = *(const float4*)&Xs[k][ty * 8];
                *(float4*)&a[4] = *(const float4*)&Xs[k][ty * 8 + 4];
                *(float4*)&bv[0] = *(const float4*)&Ws[k][tx * 4];
                #pragma unroll
                for (int i = 0; i < 8; ++i)
                    #pragma unroll
                    for (int j = 0; j < 4; ++j)
                        acc[i][j] = fmaf(a[i], bv[j], acc[i][j]);
            }
            __syncthreads();
        }
        u16* Yb = Ptb + (size_t)b * Mk * 256;
        #pragma unroll
        for (int i = 0; i < 8; ++i) {
            ushort4 o;
            o.x = f2bf(acc[i][0]);
            o.y = f2bf(acc[i][1]);
            o.z = f2bf(acc[i][2]);
            o.w = f2bf(acc[i][3]);
            *(ushort4*)&Yb[(size_t)(m0 + ty * 8 + i) * 256 + h0 + tx * 4] = o;
        }
    } else if (bid < 2432) {
        // ---- flat f32 -> bf16 convert (weights) ----
        const int cb = bid - 2304;
        const float* X = (cb < 96) ? W1 : W2;
        u16* Y = (cb < 96) ? W1b : W2b;
        const int i = ((cb < 96) ? cb : (cb - 96)) * 256 + t;
        const float4 v = *(const float4*)&X[(size_t)i * 4];
        ushort4 o;
        o.x = f2bf(v.x); o.y = f2bf(v.y); o.z = f2bf(v.z); o.w = f2bf(v.w);
        *(ushort4*)&Y[(size_t)i * 4] = o;
    } else {
        // ---- transpose + convert UF (C1, Nq) -> UFt (Nq, C1) ----
        const int f = bid - 2432;
        const int b = f >> 8, rem = f & 255;
        const int m0 = (rem >> 1) * 64, c0 = (rem & 1) * 64;
        const float* X = UF + (size_t)b * C1c * Nq;
        u16* Y = UFt + (size_t)b * Nq * C1c;
        float (*T)[65] = (float(*)[65])smem;
        const int m4 = (t & 15) * 4, cr = t >> 4;
        #pragma unroll
        for (int i = 0; i < 4; ++i) {
            const float4 v = *(const float4*)&X[(size_t)(c0 + cr + i * 16) * Nq + m0 + m4];
            T[cr + i * 16][m4 + 0] = v.x;
            T[cr + i * 16][m4 + 1] = v.y;
            T[cr + i * 16][m4 + 2] = v.z;
            T[cr + i * 16][m4 + 3] = v.w;
        }
        __syncthreads();
        const int c4 = (t & 15) * 4, mr = t >> 4;
        #pragma unroll
        for (int i = 0; i < 4; ++i) {
            const int m = mr + i * 16;
            ushort4 o;
            o.x = f2bf(T[c4 + 0][m]);
            o.y = f2bf(T[c4 + 1][m]);
            o.z = f2bf(T[c4 + 2][m]);
            o.w = f2bf(T[c4 + 3][m]);
            *(ushort4*)&Y[(size_t)(m0 + m) * C1c + c0 + c4] = o;
        }
    }
}

// ---------------- BN transform for staged B-operand (8 bf16), cvt_pk packed ----------------
__device__ __forceinline__ uint4 bnx(uint4 x, const float* scs, const float* bis, int k) {
    const u16* p = (const u16*)&x;
    const float4 s0 = *(const float4*)&scs[k];
    const float4 s1 = *(const float4*)&scs[k + 4];
    const float4 b0 = *(const float4*)&bis[k];
    const float4 b1 = *(const float4*)&bis[k + 4];
    const float* sa = (const float*)&s0;
    const float* sb = (const float*)&s1;
    const float* ba = (const float*)&b0;
    const float* bb = (const float*)&b1;
    uint4 o;
    uint32_t* po = (uint32_t*)&o;
    #pragma unroll
    for (int w2 = 0; w2 < 2; ++w2) {
        const float a0 = fmaxf(0.0f, fmaf(bf2f(p[2 * w2 + 0]), sa[2 * w2 + 0], ba[2 * w2 + 0]));
        const float a1 = fmaxf(0.0f, fmaf(bf2f(p[2 * w2 + 1]), sa[2 * w2 + 1], ba[2 * w2 + 1]));
        po[w2] = cvtpk(a0, a1);
    }
    #pragma unroll
    for (int w2 = 0; w2 < 2; ++w2) {
        const float a0 = fmaxf(0.0f, fmaf(bf2f(p[4 + 2 * w2 + 0]), sb[2 * w2 + 0], bb[2 * w2 + 0]));
        const float a1 = fmaxf(0.0f, fmaf(bf2f(p[4 + 2 * w2 + 1]), sb[2 * w2 + 1], bb[2 * w2 + 1]));
        po[2 + w2] = cvtpk(a0, a1);
    }
    return o;
}

// ================= gemm2: 128x128 MFMA bt-GEMM + gather + BN1 partial stats =================
__global__ __launch_bounds__(256) void mfma_gemm2(
    const u16* __restrict__ A, int lda, size_t sA,      // UFt
    const u16* __restrict__ Bt, int ldb,                // W1b + 256 (shared)
    u16* __restrict__ Cout,                             // y1b
    int nK,
    const u16* __restrict__ Ptb,
    const int* __restrict__ idx, const float* __restrict__ wgt,
    float* __restrict__ partS, float* __restrict__ partQ)
{
    __shared__ u16 As[4096];
    __shared__ u16 Bs[4096];
    __shared__ float sS[2][128], sQ[2][128];

    const int b = blockIdx.z;
    const int m0 = blockIdx.x * 128, n0 = blockIdx.y * 128;
    const int t = threadIdx.x;
    const int l = t & 63, wv = t >> 6;
    const int wr = wv >> 1, wc = wv & 1;

    const u16* Ab = A + (size_t)b * sA;
    const int rA0 = t >> 2, rA1 = (t + 256) >> 2;
    const int ko = (t & 3) * 8;

    f32x4 acc[4][4];
    const f32x4 z = {0.0f, 0.0f, 0.0f, 0.0f};
    #pragma unroll
    for (int i = 0; i < 4; ++i)
        #pragma unroll
        for (int j = 0; j < 4; ++j) acc[i][j] = z;

    uint4 a0 = *(const uint4*)&Ab[(size_t)(m0 + rA0) * lda + ko];
    uint4 a1 = *(const uint4*)&Ab[(size_t)(m0 + rA1) * lda + ko];
    uint4 b0 = *(const uint4*)&Bt[(size_t)(n0 + rA0) * ldb + ko];
    uint4 b1 = *(const uint4*)&Bt[(size_t)(n0 + rA1) * ldb + ko];

    for (int kt = 0; kt < nK; ++kt) {
        *(uint4*)&As[t * 8] = a0;
        *(uint4*)&As[(t + 256) * 8] = a1;
        *(uint4*)&Bs[t * 8] = b0;
        *(uint4*)&Bs[(t + 256) * 8] = b1;
        __syncthreads();
        if (kt + 1 < nK) {
            const int k0 = (kt + 1) * 32;
            a0 = *(const uint4*)&Ab[(size_t)(m0 + rA0) * lda + k0 + ko];
            a1 = *(const uint4*)&Ab[(size_t)(m0 + rA1) * lda + k0 + ko];
            b0 = *(const uint4*)&Bt[(size_t)(n0 + rA0) * ldb + k0 + ko];
            b1 = *(const uint4*)&Bt[(size_t)(n0 + rA1) * ldb + k0 + ko];
        }
        bf16x8 af[4], bf[4];
        #pragma unroll
        for (int f = 0; f < 4; ++f) {
            af[f] = *(const bf16x8*)&As[(wr * 64 + f * 16 + (l & 15)) * 32 + (l >> 4) * 8];
            bf[f] = *(const bf16x8*)&Bs[(wc * 64 + f * 16 + (l & 15)) * 32 + (l >> 4) * 8];
        }
        #pragma unroll
        for (int i = 0; i < 4; ++i)
            #pragma unroll
            for (int j = 0; j < 4; ++j)
                acc[i][j] = __builtin_amdgcn_mfma_f32_16x16x32_bf16(af[i], bf[j], acc[i][j], 0, 0, 0);
        __syncthreads();
    }

    const int cb = l & 15;
    const int rg = (l >> 4) * 4;
    float sj[4] = {0, 0, 0, 0}, qj[4] = {0, 0, 0, 0};
    #pragma unroll
    for (int i = 0; i < 4; ++i) {
        #pragma unroll
        for (int r = 0; r < 4; ++r) {
            const int R = m0 + wr * 64 + i * 16 + rg + r;
            const size_t ib = ((size_t)b * Nq + R) * 3;
            const int j0 = idx[ib], j1 = idx[ib + 1], j2 = idx[ib + 2];
            const float w0 = wgt[ib], w1 = wgt[ib + 1], w2 = wgt[ib + 2];
            const u16* Pb = Ptb + (size_t)b * Mk * 256;
            const u16* P0 = Pb + (size_t)j0 * 256;
            const u16* P1 = Pb + (size_t)j1 * 256;
            const u16* P2 = Pb + (size_t)j2 * 256;
            #pragma unroll
            for (int j = 0; j < 4; ++j) {
                const int Cc = n0 + wc * 64 + j * 16 + cb;
                float v = acc[i][j][r];
                v += w0 * bf2f(P0[Cc]) + w1 * bf2f(P1[Cc]) + w2 * bf2f(P2[Cc]);
                Cout[(size_t)b * Nq * 256 + (size_t)R * 256 + Cc] = f2bf(v);
                sj[j] += v;
                qj[j] += v * v;
            }
        }
    }

    // per-column partial sums over this block's 128 rows
    #pragma unroll
    for (int j = 0; j < 4; ++j) {
        float s = sj[j], q = qj[j];
        s += __shfl_xor(s, 16); s += __shfl_xor(s, 32);
        q += __shfl_xor(q, 16); q += __shfl_xor(q, 32);
        if (l < 16) {
            sS[wr][wc * 64 + j * 16 + l] = s;
            sQ[wr][wc * 64 + j * 16 + l] = q;
        }
    }
    __syncthreads();
    if (t < 128) {
        const float S = sS[0][t] + sS[1][t];
        const float Q = sQ[0][t] + sQ[1][t];
        const int pblk = blockIdx.z * gridDim.x + blockIdx.x;
        partS[(size_t)pblk * 256 + blockIdx.y * 128 + t] = S;
        partQ[(size_t)pblk * 256 + blockIdx.y * 128 + t] = Q;
    }
}

// ================= gemm3: 64x128 tile (2 blocks/CU), BNIN + row stats =================
// out(b, o, n) = sum_h W2b(o, h) * relu(bn1(y1b(b, n, h)));  o-tile 64, n-tile 128
__global__ __launch_bounds__(256) void mfma_gemm3(
    const u16* __restrict__ W2b,          // (128, 256)
    const u16* __restrict__ Y,            // (B, Nq, 256) bf16
    float* __restrict__ out,              // (B, 128, Nq)
    const float* __restrict__ bn_s, const float* __restrict__ bn_b,
    float* __restrict__ partS, float* __restrict__ partQ)
{
    __shared__ u16 As[2048];              // 64 rows x 32 k
    __shared__ u16 Bs[4096];              // 128 rows x 32 k
    __shared__ float scs[256], bis[256];
    __shared__ float sS[2][64], sQ[2][64];

    const int b = blockIdx.z;
    const int m0 = blockIdx.x * 64;       // o-tile
    const int n0 = blockIdx.y * 128;      // n-tile
    const int t = threadIdx.x;
    const int l = t & 63, wv = t >> 6;
    const int wr = wv >> 1, wc = wv & 1;  // wave covers 32 rows x 64 cols

    scs[t] = bn_s[t];
    bis[t] = bn_b[t];

    const u16* Yb = Y + (size_t)b * Nq * 256;
    const int rA = t >> 2;                // 0..63 (A rows)
    const int rB1 = (t + 256) >> 2;       // 64..127
    const int ko = (t & 3) * 8;

    f32x4 acc[2][4];
    const f32x4 z = {0.0f, 0.0f, 0.0f, 0.0f};
    #pragma unroll
    for (int i = 0; i < 2; ++i)
        #pragma unroll
        for (int j = 0; j < 4; ++j) acc[i][j] = z;

    uint4 a0 = *(const uint4*)&W2b[(size_t)(m0 + rA) * 256 + ko];
    uint4 b0 = *(const uint4*)&Yb[(size_t)(n0 + rA) * 256 + ko];
    uint4 b1 = *(const uint4*)&Yb[(size_t)(n0 + rB1) * 256 + ko];
    __syncthreads();  // scs/bis ready

    for (int kt = 0; kt < 8; ++kt) {
        const int k = kt * 32 + ko;
        *(uint4*)&As[t * 8] = a0;
        *(uint4*)&Bs[t * 8] = bnx(b0, scs, bis, k);
        *(uint4*)&Bs[(t + 256) * 8] = bnx(b1, scs, bis, k);
        __syncthreads();
        if (kt + 1 < 8) {
            const int k0 = (kt + 1) * 32;
            a0 = *(const uint4*)&W2b[(size_t)(m0 + rA) * 256 + k0 + ko];
            b0 = *(const uint4*)&Yb[(size_t)(n0 + rA) * 256 + k0 + ko];
            b1 = *(const uint4*)&Yb[(size_t)(n0 + rB1) * 256 + k0 + ko];
        }
        bf16x8 af[2], bf[4];
        #pragma unroll
        for (int f = 0; f < 2; ++f)
            af[f] = *(const bf16x8*)&As[(wr * 32 + f * 16 + (l & 15)) * 32 + (l >> 4) * 8];
        #pragma unroll
        for (int f = 0; f < 4; ++f)
            bf[f] = *(const bf16x8*)&Bs[(wc * 64 + f * 16 + (l & 15)) * 32 + (l >> 4) * 8];
        #pragma unroll
        for (int i = 0; i < 2; ++i)
            #pragma unroll
            for (int j = 0; j < 4; ++j)
                acc[i][j] = __builtin_amdgcn_mfma_f32_16x16x32_bf16(af[i], bf[j], acc[i][j], 0, 0, 0);
        __syncthreads();
    }

    const int cb = l & 15;
    const int rg = (l >> 4) * 4;
    float* ob = out + (size_t)b * H2c * Nq;
    #pragma unroll
    for (int i = 0; i < 2; ++i) {
        #pragma unroll
        for (int r = 0; r < 4; ++r) {
            const int Rl = wr * 32 + i * 16 + rg + r;     // local o-row [0,64)
            #pragma unroll
            for (int j = 0; j < 4; ++j) {
                const int Cc = n0 + wc * 64 + j * 16 + cb;
                ob[(size_t)(m0 + Rl) * Nq + Cc] = acc[i][j][r];
            }
            // per-row sums over this block's 128 cols
            float s = acc[i][0][r] + acc[i][1][r] + acc[i][2][r] + acc[i][3][r];
            float q = acc[i][0][r] * acc[i][0][r] + acc[i][1][r] * acc[i][1][r] +
                      acc[i][2][r] * acc[i][2][r] + acc[i][3][r] * acc[i][3][r];
            s += __shfl_xor(s, 1); s += __shfl_xor(s, 2);
            s += __shfl_xor(s, 4); s += __shfl_xor(s, 8);
            q += __shfl_xor(q, 1); q += __shfl_xor(q, 2);
            q += __shfl_xor(q, 4); q += __shfl_xor(q, 8);
            if ((l & 15) == 0) {
                sS[wc][Rl] = s;
                sQ[wc][Rl] = q;
            }
        }
    }
    __syncthreads();
    if (t < 64) {
        const float S = sS[0][t] + sS[1][t];
        const float Q = sQ[0][t] + sQ[1][t];
        const int p = blockIdx.z * gridDim.y + blockIdx.y;   // [0,256)
        partS[(size_t)p * 128 + m0 + t] = S;
        partQ[(size_t)p * 128 + m0 + t] = Q;
    }
}

// ---------------- BN finalize: reduce partials -> scale/bias ----------------
__global__ __launch_bounds__(1024) void bn_finalize(
    const float* __restrict__ pS, const float* __restrict__ pQ,
    const float* __restrict__ g, const float* __restrict__ beta,
    float* __restrict__ scale, float* __restrict__ bias,
    int C, int np, float cnt)
{
    __shared__ float rs[1024], rq[1024];
    const int t = threadIdx.x;
    const int c = t & (C - 1);
    const int sl = t / C;
    const int nsl = 1024 / C;
    float s = 0.0f, q = 0.0f;
    for (int i = sl; i < np; i += nsl) {
        s += pS[(size_t)i * C + c];
        q += pQ[(size_t)i * C + c];
    }
    rs[t] = s;
    rq[t] = q;
    __syncthreads();
    if (t < C) {
        for (int k = 1; k < nsl; ++k) {
            s += rs[t + k * C];
            q += rq[t + k * C];
        }
        const float mean = s / cnt;
        const float var = q / cnt - mean * mean;
        const float r = rsqrtf(var + 1e-5f);
        const float sc = g[t] * r;
        scale[t] = sc;
        bias[t] = beta[t] - mean * sc;
    }
}

// ---------------- fused BN2 finalize + apply ----------------
__global__ __launch_bounds__(256) void bn2_apply_kernel(
    float* __restrict__ Y,
    const float* __restrict__ pS, const float* __restrict__ pQ,
    const float* __restrict__ g, const float* __restrict__ beta)
{
    __shared__ float rs[256], rq[256];
    const int t = threadIdx.x;
    const size_t base = (size_t)blockIdx.x * 1024;
    const int c = (int)((base / Nq) % H2c);

    rs[t] = pS[(size_t)t * 128 + c];
    rq[t] = pQ[(size_t)t * 128 + c];
    __syncthreads();
    for (int off = 128; off > 0; off >>= 1) {
        if (t < off) {
            rs[t] += rs[t + off];
            rq[t] += rq[t + off];
        }
        __syncthreads();
    }
    if (t == 0) {
        const float cnt = (float)(Bn * Nq);
        const float mean = rs[0] / cnt;
        const float var = rq[0] / cnt - mean * mean;
        const float r = rsqrtf(var + 1e-5f);
        const float sc = g[c] * r;
        rs[0] = sc;
        rq[0] = beta[c] - mean * sc;
    }
    __syncthreads();
    const float sc = rs[0], bi = rq[0];
    float4 v = *(float4*)&Y[base + t * 4];
    v.x = fmaxf(0.0f, fmaf(v.x, sc, bi));
    v.y = fmaxf(0.0f, fmaf(v.y, sc, bi));
    v.z = fmaxf(0.0f, fmaf(v.z, sc, bi));
    v.w = fmaxf(0.0f, fmaf(v.w, sc, bi));
    *(float4*)&Y[base + t * 4] = v;
}

extern "C" void kernel_launch(void* const* d_in, const int* in_sizes, int n_in,
                              void* d_out, int out_size, void* d_ws, size_t ws_size,
                              hipStream_t stream) {
    const float* unknown = (const float*)d_in[0];
    const float* known = (const float*)d_in[1];
    const float* unknow_feats = (const float*)d_in[2];
    const float* known_feats = (const float*)d_in[3];
    const float* W1 = (const float*)d_in[4];
    const float* g1 = (const float*)d_in[5];
    const float* b1 = (const float*)d_in[6];
    const float* W2 = (const float*)d_in[7];
    const float* g2 = (const float*)d_in[8];
    const float* b2 = (const float*)d_in[9];
    float* out = (float*)d_out;

    char* w = (char*)d_ws;
    u16* UFt = (u16*)w; w += (size_t)Bn * Nq * C1c * 2;
    u16* W1b = (u16*)w; w += (size_t)H1c * 384 * 2;
    u16* W2b = (u16*)w; w += (size_t)H2c * H1c * 2;
    u16* Ptb = (u16*)w; w += (size_t)Bn * Mk * H1c * 2;
    u16* y1b = (u16*)w; w += (size_t)Bn * Nq * H1c * 2;
    int* idx = (int*)w; w += (size_t)Bn * Nq * 3 * 4;
    float* wgt = (float*)w; w += (size_t)Bn * Nq * 3 * 4;
    float* pS1 = (float*)w; w += (size_t)256 * 256 * 4;
    float* pQ1 = (float*)w; w += (size_t)256 * 256 * 4;
    float* pS2 = (float*)w; w += (size_t)256 * 128 * 4;
    float* pQ2 = (float*)w; w += (size_t)256 * 128 * 4;
    float* scale1 = (float*)w; w += 1024;
    float* bias1 = (float*)w; w += 1024;

    // 1) K1: knn + f32 gemm1 (KF,W1 -> Ptb) + weight cvt + UF transpose
    knn_prep_kernel<<<3456, 256, 0, stream>>>(W1, W2, W1b, W2b,
                                              known_feats, Ptb, unknow_feats, UFt,
                                              unknown, known, idx, wgt);

    // 2) gemm2: y1b(b,n,h) = UFt(b,n,:) @ W1[:,256:]^T + gather(Ptb)  [+ BN1 stats]
    mfma_gemm2<<<dim3(Nq / 128, H1c / 128, Bn), 256, 0, stream>>>(
        UFt, C1c, (size_t)Nq * C1c,
        W1b + C2c, 384,
        y1b, C1c / 32,
        Ptb, idx, wgt, pS1, pQ1);

    // 3) BN1 finalize -> scale1/bias1
    bn_finalize<<<1, 1024, 0, stream>>>(pS1, pQ1, g1, b1, scale1, bias1,
                                        H1c, 256, (float)(Bn * Nq));

    // 4) gemm3 (64x128 tile, 2 blocks/CU): out = W2 @ relu(bn1(y1b))^T  [+ BN2 stats]
    mfma_gemm3<<<dim3(2, Nq / 128, Bn), 256, 0, stream>>>(
        W2b, y1b, out, scale1, bias1, pS2, pQ2);

    // 5) BN2 finalize (per-block) + apply in place
    bn2_apply_kernel<<<(Bn * H2c * Nq) / 1024, 256, 0, stream>>>(out, pS2, pQ2, g2, b2);
}

// Round 10
// 104.842 us; speedup vs baseline: 1.2392x; 1.2392x over previous
//
#include <hip/hip_runtime.h>
#include <hip/hip_bf16.h>
#include <cstdint>
#include <cstddef>

typedef unsigned short u16;
typedef __attribute__((ext_vector_type(8))) short bf16x8;
typedef __attribute__((ext_vector_type(4))) float f32x4;

constexpr int Bn = 4;
constexpr int Nq = 8192;
constexpr int Mk = 2048;
constexpr int C1c = 128;
constexpr int C2c = 256;
constexpr int H1c = 256;
constexpr int H2c = 128;

__device__ __forceinline__ float bf2f(u16 u) {
    union { uint32_t i; float f; } v;
    v.i = (uint32_t)u << 16;
    return v.f;
}
__device__ __forceinline__ u16 f2bf(float f) {
    const uint32_t x = __float_as_uint(f);
    return (u16)((x + 0x7FFFu + ((x >> 16) & 1u)) >> 16);
}
__device__ __forceinline__ uint32_t cvtpk(float lo, float hi) {
    uint32_t r;
    asm("v_cvt_pk_bf16_f32 %0, %1, %2" : "=v"(r) : "v"(lo), "v"(hi));
    return r;
}

// ================= fused knn + prep (round-6 proven form) =================
// block ranges (knn FIRST — long pole starts at t=0):
// [0,1024) knn (8 lanes/query) | [1024,1152) cvt W1/W2 | [1152,1664) KF | [1664,2688) UF
__global__ __launch_bounds__(256) void knn_prep_kernel(
    const float* __restrict__ W1, const float* __restrict__ W2,
    u16* __restrict__ W1b, u16* __restrict__ W2b,
    const float* __restrict__ KF, u16* __restrict__ KFt,
    const float* __restrict__ UF, u16* __restrict__ UFt,
    const float* __restrict__ unknown, const float* __restrict__ known,
    int* __restrict__ idx_out, float* __restrict__ w_out)
{
    __shared__ __align__(16) char smem[32768];
    const int bid = blockIdx.x;
    const int t = threadIdx.x;

    if (bid < 1024) {
        // ---- 3-NN: exact f32 compare, 8 lanes/query ----
        float4* kp = (float4*)smem;  // (x, y, z, |k|^2), 32 KB
        const int b = bid >> 8;
        const int n0 = (bid & 255) * 32;

        const float* kb = known + (size_t)b * Mk * 3;
        for (int i = t; i < Mk; i += 256) {
            const float x = kb[i * 3 + 0], y = kb[i * 3 + 1], z = kb[i * 3 + 2];
            kp[i] = make_float4(x, y, z, fmaf(x, x, fmaf(y, y, z * z)));
        }
        __syncthreads();

        const int q = n0 + (t >> 3);
        const int s = t & 7;
        const float* u = unknown + ((size_t)b * Nq + q) * 3;
        const float ux = u[0], uy = u[1], uz = u[2];
        const float nux = -2.0f * ux, nuy = -2.0f * uy, nuz = -2.0f * uz;
        const float uu = fmaf(ux, ux, fmaf(uy, uy, uz * uz));

        // track d' = |k|^2 - 2 u.k  (ordering identical to true squared distance)
        float d0 = 1e30f, d1 = 1e30f, d2 = 1e30f;
        int i0 = 0, i1 = 0, i2 = 0;

        auto ins = [&](float d, int i) {
            const bool c0 = d < d0, c1 = d < d1, c2 = d < d2;
            const float nd0 = fminf(d0, d);
            const float nd1 = __builtin_amdgcn_fmed3f(d0, d, d1);
            const float nd2 = __builtin_amdgcn_fmed3f(d1, d, d2);
            i2 = c1 ? i1 : (c2 ? i : i2);
            i1 = c0 ? i0 : (c1 ? i : i1);
            i0 = c0 ? i : i0;
            d0 = nd0; d1 = nd1; d2 = nd2;
        };

        #pragma unroll 8
        for (int it = 0; it < Mk / 8; ++it) {
            const int m = it * 8 + s;  // 8 consecutive float4 slots: conflict-free
            const float4 p = kp[m];
            const float d = fmaf(nux, p.x, fmaf(nuy, p.y, fmaf(nuz, p.z, p.w)));
            ins(d, m);
        }
        #pragma unroll
        for (int off = 1; off <= 4; off <<= 1) {
            const float e0 = __shfl_xor(d0, off), e1 = __shfl_xor(d1, off), e2 = __shfl_xor(d2, off);
            const int j0 = __shfl_xor(i0, off), j1 = __shfl_xor(i1, off), j2 = __shfl_xor(i2, off);
            ins(e0, j0);
            ins(e1, j1);
            ins(e2, j2);
        }
        if (s == 0) {
            const float f0 = d0 + uu, f1 = d1 + uu, f2 = d2 + uu;
            const float r0 = 1.0f / (f0 + 1e-8f);
            const float r1 = 1.0f / (f1 + 1e-8f);
            const float r2 = 1.0f / (f2 + 1e-8f);
            const float inv = 1.0f / (r0 + r1 + r2);
            const size_t base = ((size_t)b * Nq + q) * 3;
            idx_out[base + 0] = i0;
            idx_out[base + 1] = i1;
            idx_out[base + 2] = i2;
            w_out[base + 0] = r0 * inv;
            w_out[base + 1] = r1 * inv;
            w_out[base + 2] = r2 * inv;
        }
    } else if (bid < 1152) {
        // ---- flat f32 -> bf16 convert (weights) ----
        const int cb = bid - 1024;
        const float* X = (cb < 96) ? W1 : W2;
        u16* Y = (cb < 96) ? W1b : W2b;
        const int i = ((cb < 96) ? cb : (cb - 96)) * 256 + t;
        const float4 v = *(const float4*)&X[(size_t)i * 4];
        ushort4 o;
        o.x = f2bf(v.x); o.y = f2bf(v.y); o.z = f2bf(v.z); o.w = f2bf(v.w);
        *(ushort4*)&Y[(size_t)i * 4] = o;
    } else {
        // ---- transpose + convert: X (C, M) tile -> Y (M, C) ----
        const float* X;
        u16* Y;
        int C, M, m0, c0;
        if (bid < 1664) {
            const int f = bid - 1152;
            const int b = f >> 7, rem = f & 127;
            C = C2c; M = Mk; m0 = (rem >> 2) * 64; c0 = (rem & 3) * 64;
            X = KF + (size_t)b * C * M;
            Y = KFt + (size_t)b * M * C;
        } else {
            const int f = bid - 1664;
            const int b = f >> 8, rem = f & 255;
            C = C1c; M = Nq; m0 = (rem >> 1) * 64; c0 = (rem & 1) * 64;
            X = UF + (size_t)b * C * M;
            Y = UFt + (size_t)b * M * C;
        }
        float (*T)[65] = (float(*)[65])smem;
        const int m4 = (t & 15) * 4, cr = t >> 4;
        #pragma unroll
        for (int i = 0; i < 4; ++i) {
            const float4 v = *(const float4*)&X[(size_t)(c0 + cr + i * 16) * M + m0 + m4];
            T[cr + i * 16][m4 + 0] = v.x;
            T[cr + i * 16][m4 + 1] = v.y;
            T[cr + i * 16][m4 + 2] = v.z;
            T[cr + i * 16][m4 + 3] = v.w;
        }
        __syncthreads();
        const int c4 = (t & 15) * 4, mr = t >> 4;
        #pragma unroll
        for (int i = 0; i < 4; ++i) {
            const int m = mr + i * 16;
            ushort4 o;
            o.x = f2bf(T[c4 + 0][m]);
            o.y = f2bf(T[c4 + 1][m]);
            o.z = f2bf(T[c4 + 2][m]);
            o.w = f2bf(T[c4 + 3][m]);
            *(ushort4*)&Y[(size_t)(m0 + m) * C + c0 + c4] = o;
        }
    }
}

// ---------------- BN transform for staged B-operand (8 bf16), cvt_pk packed ----------------
__device__ __forceinline__ uint4 bnx(uint4 x, const float* scs, const float* bis, int k) {
    const u16* p = (const u16*)&x;
    const float4 s0 = *(const float4*)&scs[k];
    const float4 s1 = *(const float4*)&scs[k + 4];
    const float4 b0 = *(const float4*)&bis[k];
    const float4 b1 = *(const float4*)&bis[k + 4];
    const float* sa = (const float*)&s0;
    const float* sb = (const float*)&s1;
    const float* ba = (const float*)&b0;
    const float* bb = (const float*)&b1;
    uint4 o;
    uint32_t* po = (uint32_t*)&o;
    #pragma unroll
    for (int w2 = 0; w2 < 2; ++w2) {
        const float a0 = fmaxf(0.0f, fmaf(bf2f(p[2 * w2 + 0]), sa[2 * w2 + 0], ba[2 * w2 + 0]));
        const float a1 = fmaxf(0.0f, fmaf(bf2f(p[2 * w2 + 1]), sa[2 * w2 + 1], ba[2 * w2 + 1]));
        po[w2] = cvtpk(a0, a1);
    }
    #pragma unroll
    for (int w2 = 0; w2 < 2; ++w2) {
        const float a0 = fmaxf(0.0f, fmaf(bf2f(p[4 + 2 * w2 + 0]), sb[2 * w2 + 0], bb[2 * w2 + 0]));
        const float a1 = fmaxf(0.0f, fmaf(bf2f(p[4 + 2 * w2 + 1]), sb[2 * w2 + 1], bb[2 * w2 + 1]));
        po[2 + w2] = cvtpk(a0, a1);
    }
    return o;
}

// ================= bf16 MFMA bt-GEMM 128x128 (gemm1: plain, gemm2: gather+stats) =================
template <int GATHER, int STATS>
__global__ __launch_bounds__(256) void mfma_gemm(
    const u16* __restrict__ A, int lda, size_t sA,
    const u16* __restrict__ Bt, int ldb, size_t sB,
    u16* __restrict__ Cout, int ldc, size_t sC,
    int nK,
    const u16* __restrict__ Ptb,
    const int* __restrict__ idx, const float* __restrict__ wgt, int nrows,
    float* __restrict__ partS, float* __restrict__ partQ)
{
    __shared__ u16 As[4096];
    __shared__ u16 Bs[4096];
    __shared__ float sS[2][128], sQ[2][128];

    const int b = blockIdx.z;
    const int m0 = blockIdx.x * 128, n0 = blockIdx.y * 128;
    const int t = threadIdx.x;
    const int l = t & 63, wv = t >> 6;
    const int wr = wv >> 1, wc = wv & 1;

    const u16* Ab = A + (size_t)b * sA;
    const u16* Btb = Bt + (size_t)b * sB;
    const int rA0 = t >> 2, rA1 = (t + 256) >> 2;
    const int ko = (t & 3) * 8;

    f32x4 acc[4][4];
    const f32x4 z = {0.0f, 0.0f, 0.0f, 0.0f};
    #pragma unroll
    for (int i = 0; i < 4; ++i)
        #pragma unroll
        for (int j = 0; j < 4; ++j) acc[i][j] = z;

    uint4 a0 = *(const uint4*)&Ab[(size_t)(m0 + rA0) * lda + ko];
    uint4 a1 = *(const uint4*)&Ab[(size_t)(m0 + rA1) * lda + ko];
    uint4 b0 = *(const uint4*)&Btb[(size_t)(n0 + rA0) * ldb + ko];
    uint4 b1 = *(const uint4*)&Btb[(size_t)(n0 + rA1) * ldb + ko];

    for (int kt = 0; kt < nK; ++kt) {
        *(uint4*)&As[t * 8] = a0;
        *(uint4*)&As[(t + 256) * 8] = a1;
        *(uint4*)&Bs[t * 8] = b0;
        *(uint4*)&Bs[(t + 256) * 8] = b1;
        __syncthreads();
        if (kt + 1 < nK) {
            const int k0 = (kt + 1) * 32;
            a0 = *(const uint4*)&Ab[(size_t)(m0 + rA0) * lda + k0 + ko];
            a1 = *(const uint4*)&Ab[(size_t)(m0 + rA1) * lda + k0 + ko];
            b0 = *(const uint4*)&Btb[(size_t)(n0 + rA0) * ldb + k0 + ko];
            b1 = *(const uint4*)&Btb[(size_t)(n0 + rA1) * ldb + k0 + ko];
        }
        bf16x8 af[4], bf[4];
        #pragma unroll
        for (int f = 0; f < 4; ++f) {
            af[f] = *(const bf16x8*)&As[(wr * 64 + f * 16 + (l & 15)) * 32 + (l >> 4) * 8];
            bf[f] = *(const bf16x8*)&Bs[(wc * 64 + f * 16 + (l & 15)) * 32 + (l >> 4) * 8];
        }
        #pragma unroll
        for (int i = 0; i < 4; ++i)
            #pragma unroll
            for (int j = 0; j < 4; ++j)
                acc[i][j] = __builtin_amdgcn_mfma_f32_16x16x32_bf16(af[i], bf[j], acc[i][j], 0, 0, 0);
        __syncthreads();
    }

    const int cb = l & 15;
    const int rg = (l >> 4) * 4;
    float sj[4] = {0, 0, 0, 0}, qj[4] = {0, 0, 0, 0};
    #pragma unroll
    for (int i = 0; i < 4; ++i) {
        #pragma unroll
        for (int r = 0; r < 4; ++r) {
            const int R = m0 + wr * 64 + i * 16 + rg + r;
            const u16 *P0 = nullptr, *P1 = nullptr, *P2 = nullptr;
            float w0 = 0.0f, w1 = 0.0f, w2 = 0.0f;
            if (GATHER) {
                const size_t ib = ((size_t)b * nrows + R) * 3;
                const int j0 = idx[ib], j1 = idx[ib + 1], j2 = idx[ib + 2];
                w0 = wgt[ib];
                w1 = wgt[ib + 1];
                w2 = wgt[ib + 2];
                const u16* Pb = Ptb + (size_t)b * Mk * 256;
                P0 = Pb + (size_t)j0 * 256;
                P1 = Pb + (size_t)j1 * 256;
                P2 = Pb + (size_t)j2 * 256;
            }
            #pragma unroll
            for (int j = 0; j < 4; ++j) {
                const int Cc = n0 + wc * 64 + j * 16 + cb;
                float v = acc[i][j][r];
                if (GATHER)
                    v += w0 * bf2f(P0[Cc]) + w1 * bf2f(P1[Cc]) + w2 * bf2f(P2[Cc]);
                Cout[(size_t)b * sC + (size_t)R * ldc + Cc] = f2bf(v);
                if (STATS) {
                    sj[j] += v;
                    qj[j] += v * v;
                }
            }
        }
    }

    if (STATS) {
        #pragma unroll
        for (int j = 0; j < 4; ++j) {
            float s = sj[j], q = qj[j];
            s += __shfl_xor(s, 16); s += __shfl_xor(s, 32);
            q += __shfl_xor(q, 16); q += __shfl_xor(q, 32);
            if (l < 16) {
                sS[wr][wc * 64 + j * 16 + l] = s;
                sQ[wr][wc * 64 + j * 16 + l] = q;
            }
        }
        __syncthreads();
        if (t < 128) {
            const float S = sS[0][t] + sS[1][t];
            const float Q = sQ[0][t] + sQ[1][t];
            const int pblk = blockIdx.z * gridDim.x + blockIdx.x;
            partS[(size_t)pblk * 256 + blockIdx.y * 128 + t] = S;
            partQ[(size_t)pblk * 256 + blockIdx.y * 128 + t] = Q;
        }
    }
}

// ================= gemm3: 64x128 tile (2 blocks/CU), BNIN + row stats =================
__global__ __launch_bounds__(256) void mfma_gemm3(
    const u16* __restrict__ W2b,          // (128, 256)
    const u16* __restrict__ Y,            // (B, Nq, 256) bf16
    float* __restrict__ out,              // (B, 128, Nq)
    const float* __restrict__ bn_s, const float* __restrict__ bn_b,
    float* __restrict__ partS, float* __restrict__ partQ)
{
    __shared__ u16 As[2048];              // 64 rows x 32 k
    __shared__ u16 Bs[4096];              // 128 rows x 32 k
    __shared__ float scs[256], bis[256];
    __shared__ float sS[2][64], sQ[2][64];

    const int b = blockIdx.z;
    const int m0 = blockIdx.x * 64;       // o-tile
    const int n0 = blockIdx.y * 128;      // n-tile
    const int t = threadIdx.x;
    const int l = t & 63, wv = t >> 6;
    const int wr = wv >> 1, wc = wv & 1;  // wave covers 32 rows x 64 cols

    scs[t] = bn_s[t];
    bis[t] = bn_b[t];

    const u16* Yb = Y + (size_t)b * Nq * 256;
    const int rA = t >> 2;                // 0..63
    const int rB1 = (t + 256) >> 2;       // 64..127
    const int ko = (t & 3) * 8;

    f32x4 acc[2][4];
    const f32x4 z = {0.0f, 0.0f, 0.0f, 0.0f};
    #pragma unroll
    for (int i = 0; i < 2; ++i)
        #pragma unroll
        for (int j = 0; j < 4; ++j) acc[i][j] = z;

    uint4 a0 = *(const uint4*)&W2b[(size_t)(m0 + rA) * 256 + ko];
    uint4 b0 = *(const uint4*)&Yb[(size_t)(n0 + rA) * 256 + ko];
    uint4 b1 = *(const uint4*)&Yb[(size_t)(n0 + rB1) * 256 + ko];
    __syncthreads();  // scs/bis ready

    for (int kt = 0; kt < 8; ++kt) {
        const int k = kt * 32 + ko;
        *(uint4*)&As[t * 8] = a0;
        *(uint4*)&Bs[t * 8] = bnx(b0, scs, bis, k);
        *(uint4*)&Bs[(t + 256) * 8] = bnx(b1, scs, bis, k);
        __syncthreads();
        if (kt + 1 < 8) {
            const int k0 = (kt + 1) * 32;
            a0 = *(const uint4*)&W2b[(size_t)(m0 + rA) * 256 + k0 + ko];
            b0 = *(const uint4*)&Yb[(size_t)(n0 + rA) * 256 + k0 + ko];
            b1 = *(const uint4*)&Yb[(size_t)(n0 + rB1) * 256 + k0 + ko];
        }
        bf16x8 af[2], bf[4];
        #pragma unroll
        for (int f = 0; f < 2; ++f)
            af[f] = *(const bf16x8*)&As[(wr * 32 + f * 16 + (l & 15)) * 32 + (l >> 4) * 8];
        #pragma unroll
        for (int f = 0; f < 4; ++f)
            bf[f] = *(const bf16x8*)&Bs[(wc * 64 + f * 16 + (l & 15)) * 32 + (l >> 4) * 8];
        #pragma unroll
        for (int i = 0; i < 2; ++i)
            #pragma unroll
            for (int j = 0; j < 4; ++j)
                acc[i][j] = __builtin_amdgcn_mfma_f32_16x16x32_bf16(af[i], bf[j], acc[i][j], 0, 0, 0);
        __syncthreads();
    }

    const int cb = l & 15;
    const int rg = (l >> 4) * 4;
    float* ob = out + (size_t)b * H2c * Nq;
    #pragma unroll
    for (int i = 0; i < 2; ++i) {
        #pragma unroll
        for (int r = 0; r < 4; ++r) {
            const int Rl = wr * 32 + i * 16 + rg + r;     // local o-row [0,64)
            #pragma unroll
            for (int j = 0; j < 4; ++j) {
                const int Cc = n0 + wc * 64 + j * 16 + cb;
                ob[(size_t)(m0 + Rl) * Nq + Cc] = acc[i][j][r];
            }
            float s = acc[i][0][r] + acc[i][1][r] + acc[i][2][r] + acc[i][3][r];
            float q = acc[i][0][r] * acc[i][0][r] + acc[i][1][r] * acc[i][1][r] +
                      acc[i][2][r] * acc[i][2][r] + acc[i][3][r] * acc[i][3][r];
            s += __shfl_xor(s, 1); s += __shfl_xor(s, 2);
            s += __shfl_xor(s, 4); s += __shfl_xor(s, 8);
            q += __shfl_xor(q, 1); q += __shfl_xor(q, 2);
            q += __shfl_xor(q, 4); q += __shfl_xor(q, 8);
            if ((l & 15) == 0) {
                sS[wc][Rl] = s;
                sQ[wc][Rl] = q;
            }
        }
    }
    __syncthreads();
    if (t < 64) {
        const float S = sS[0][t] + sS[1][t];
        const float Q = sQ[0][t] + sQ[1][t];
        const int p = blockIdx.z * gridDim.y + blockIdx.y;   // [0,256)
        partS[(size_t)p * 128 + m0 + t] = S;
        partQ[(size_t)p * 128 + m0 + t] = Q;
    }
}

// ---------------- BN1 finalize: reduce partials -> scale/bias ----------------
__global__ __launch_bounds__(1024) void bn_finalize(
    const float* __restrict__ pS, const float* __restrict__ pQ,
    const float* __restrict__ g, const float* __restrict__ beta,
    float* __restrict__ scale, float* __restrict__ bias,
    int C, int np, float cnt)
{
    __shared__ float rs[1024], rq[1024];
    const int t = threadIdx.x;
    const int c = t & (C - 1);
    const int sl = t / C;
    const int nsl = 1024 / C;
    float s = 0.0f, q = 0.0f;
    for (int i = sl; i < np; i += nsl) {
        s += pS[(size_t)i * C + c];
        q += pQ[(size_t)i * C + c];
    }
    rs[t] = s;
    rq[t] = q;
    __syncthreads();
    if (t < C) {
        for (int k = 1; k < nsl; ++k) {
            s += rs[t + k * C];
            q += rq[t + k * C];
        }
        const float mean = s / cnt;
        const float var = q / cnt - mean * mean;
        const float r = rsqrtf(var + 1e-5f);
        const float sc = g[t] * r;
        scale[t] = sc;
        bias[t] = beta[t] - mean * sc;
    }
}

// ---------------- fused BN2 finalize + apply ----------------
__global__ __launch_bounds__(256) void bn2_apply_kernel(
    float* __restrict__ Y,
    const float* __restrict__ pS, const float* __restrict__ pQ,
    const float* __restrict__ g, const float* __restrict__ beta)
{
    __shared__ float rs[256], rq[256];
    const int t = threadIdx.x;
    const size_t base = (size_t)blockIdx.x * 1024;
    const int c = (int)((base / Nq) % H2c);

    rs[t] = pS[(size_t)t * 128 + c];
    rq[t] = pQ[(size_t)t * 128 + c];
    __syncthreads();
    for (int off = 128; off > 0; off >>= 1) {
        if (t < off) {
            rs[t] += rs[t + off];
            rq[t] += rq[t + off];
        }
        __syncthreads();
    }
    if (t == 0) {
        const float cnt = (float)(Bn * Nq);
        const float mean = rs[0] / cnt;
        const float var = rq[0] / cnt - mean * mean;
        const float r = rsqrtf(var + 1e-5f);
        const float sc = g[c] * r;
        rs[0] = sc;
        rq[0] = beta[c] - mean * sc;
    }
    __syncthreads();
    const float sc = rs[0], bi = rq[0];
    float4 v = *(float4*)&Y[base + t * 4];
    v.x = fmaxf(0.0f, fmaf(v.x, sc, bi));
    v.y = fmaxf(0.0f, fmaf(v.y, sc, bi));
    v.z = fmaxf(0.0f, fmaf(v.z, sc, bi));
    v.w = fmaxf(0.0f, fmaf(v.w, sc, bi));
    *(float4*)&Y[base + t * 4] = v;
}

extern "C" void kernel_launch(void* const* d_in, const int* in_sizes, int n_in,
                              void* d_out, int out_size, void* d_ws, size_t ws_size,
                              hipStream_t stream) {
    const float* unknown = (const float*)d_in[0];
    const float* known = (const float*)d_in[1];
    const float* unknow_feats = (const float*)d_in[2];
    const float* known_feats = (const float*)d_in[3];
    const float* W1 = (const float*)d_in[4];
    const float* g1 = (const float*)d_in[5];
    const float* b1 = (const float*)d_in[6];
    const float* W2 = (const float*)d_in[7];
    const float* g2 = (const float*)d_in[8];
    const float* b2 = (const float*)d_in[9];
    float* out = (float*)d_out;

    char* w = (char*)d_ws;
    u16* KFt = (u16*)w; w += (size_t)Bn * Mk * C2c * 2;
    u16* UFt = (u16*)w; w += (size_t)Bn * Nq * C1c * 2;
    u16* W1b = (u16*)w; w += (size_t)H1c * 384 * 2;
    u16* W2b = (u16*)w; w += (size_t)H2c * H1c * 2;
    u16* Ptb = (u16*)w; w += (size_t)Bn * Mk * H1c * 2;
    u16* y1b = (u16*)w; w += (size_t)Bn * Nq * H1c * 2;
    int* idx = (int*)w; w += (size_t)Bn * Nq * 3 * 4;
    float* wgt = (float*)w; w += (size_t)Bn * Nq * 3 * 4;
    float* pS1 = (float*)w; w += (size_t)256 * 256 * 4;
    float* pQ1 = (float*)w; w += (size_t)256 * 256 * 4;
    float* pS2 = (float*)w; w += (size_t)256 * 128 * 4;
    float* pQ2 = (float*)w; w += (size_t)256 * 128 * 4;
    float* scale1 = (float*)w; w += 1024;
    float* bias1 = (float*)w; w += 1024;

    // 1) fused knn (first) + prep (weight cvt + feat transposes)
    knn_prep_kernel<<<2688, 256, 0, stream>>>(W1, W2, W1b, W2b,
                                              known_feats, KFt, unknow_feats, UFt,
                                              unknown, known, idx, wgt);

    // 2) gemm1: Ptb(b,m,h) = KFt(b,m,:) @ W1[:, :256]^T
    mfma_gemm<0, 0><<<dim3(Mk / 128, H1c / 128, Bn), 256, 0, stream>>>(
        KFt, C2c, (size_t)Mk * C2c,
        W1b, 384, 0,
        Ptb, H1c, (size_t)Mk * H1c,
        C2c / 32, nullptr, nullptr, nullptr, 0, nullptr, nullptr);

    // 3) gemm2: y1b(b,n,h) = UFt(b,n,:) @ W1[:,256:]^T + gather(Ptb)  [+ BN1 stats]
    mfma_gemm<1, 1><<<dim3(Nq / 128, H1c / 128, Bn), 256, 0, stream>>>(
        UFt, C1c, (size_t)Nq * C1c,
        W1b + C2c, 384, 0,
        y1b, H1c, (size_t)Nq * H1c,
        C1c / 32, Ptb, idx, wgt, Nq, pS1, pQ1);

    // 4) BN1 finalize -> scale1/bias1
    bn_finalize<<<1, 1024, 0, stream>>>(pS1, pQ1, g1, b1, scale1, bias1,
                                        H1c, 256, (float)(Bn * Nq));

    // 5) gemm3 (64x128 tile, 2 blocks/CU): out = W2 @ relu(bn1(y1b))^T  [+ BN2 stats]
    mfma_gemm3<<<dim3(2, Nq / 128, Bn), 256, 0, stream>>>(
        W2b, y1b, out, scale1, bias1, pS2, pQ2);

    // 6) BN2 finalize (per-block) + apply in place
    bn2_apply_kernel<<<(Bn * H2c * Nq) / 1024, 256, 0, stream>>>(out, pS2, pQ2, g2, b2);
}